// Round 6
// baseline (232.733 us; speedup 1.0000x reference)
//
#include <hip/hip_runtime.h>
#include <stdint.h>

#define NB 4
#define SS 1024
#define DD 1024
#define EE 4
#define HH 16
#define HDD 64
#define NN (NB*SS)      // 4096 tokens
#define KK2 (EE*DD)     // 4096 expanded K
#define FF1 (3*DD)      // 3072

typedef __attribute__((ext_vector_type(4))) float f32x4;
typedef __attribute__((ext_vector_type(16))) float f32x16;
typedef __attribute__((ext_vector_type(8))) _Float16 half8;
typedef __attribute__((ext_vector_type(4))) _Float16 half4;

static __device__ __forceinline__ f32x4 mfma16(half8 a, half8 b, f32x4 c){
  return __builtin_amdgcn_mfma_f32_16x16x32_f16(a, b, c, 0, 0, 0);
}
static __device__ __forceinline__ f32x16 mfma32(half8 a, half8 b, f32x16 c){
  return __builtin_amdgcn_mfma_f32_32x32x16_f16(a, b, c, 0, 0, 0);
}

// async global->LDS, 16B per lane; LDS dest = wave-uniform base + lane*16
#define GLOAD_LDS16(gp, lp) __builtin_amdgcn_global_load_lds( \
    (const unsigned int __attribute__((address_space(1)))*)(uintptr_t)(gp), \
    (unsigned int __attribute__((address_space(3)))*)(uintptr_t)(lp), 16, 0, 0)

#define SBAR() do { asm volatile("" ::: "memory"); \
                    __builtin_amdgcn_s_barrier(); \
                    asm volatile("" ::: "memory"); } while(0)

// ---------------- kernel 1: router softmax + LN stats + xn (f16) -----------
__global__ __launch_bounds__(256) void prep_kernel(
    const float* __restrict__ x, const float* __restrict__ Wr,
    const float* __restrict__ br, float* __restrict__ score,
    _Float16* __restrict__ xnb)
{
  int n = blockIdx.x;
  int tid = threadIdx.x;
  float4 xv = ((const float4*)(x + (size_t)n*DD))[tid];   // d = tid*4..+3
  float xa[4] = {xv.x, xv.y, xv.z, xv.w};
  float vals[6];
  vals[0] = xa[0]+xa[1]+xa[2]+xa[3];
  vals[1] = xa[0]*xa[0]+xa[1]*xa[1]+xa[2]*xa[2]+xa[3]*xa[3];
  vals[2] = vals[3] = vals[4] = vals[5] = 0.f;
  #pragma unroll
  for (int j = 0; j < 4; ++j){
    float4 w = ((const float4*)Wr)[tid*4 + j];  // Wr row d = 4 expert weights
    vals[2] += xa[j]*w.x; vals[3] += xa[j]*w.y;
    vals[4] += xa[j]*w.z; vals[5] += xa[j]*w.w;
  }
  #pragma unroll
  for (int off = 32; off >= 1; off >>= 1)
    #pragma unroll
    for (int i = 0; i < 6; ++i)
      vals[i] += __shfl_xor(vals[i], off, 64);
  __shared__ float red[4][6];
  int wid = tid >> 6;
  if ((tid & 63) == 0){
    #pragma unroll
    for (int i = 0; i < 6; ++i) red[wid][i] = vals[i];
  }
  __syncthreads();
  float tot[6];
  #pragma unroll
  for (int i = 0; i < 6; ++i)
    tot[i] = red[0][i] + red[1][i] + red[2][i] + red[3][i];

  float mu   = tot[0] * (1.f/DD);
  float var  = tot[1] * (1.f/DD) - mu*mu;
  float rsig = rsqrtf(var + 1e-5f);
  float lg[4];
  #pragma unroll
  for (int e = 0; e < 4; ++e) lg[e] = tot[2+e] + br[e];
  float mx = fmaxf(fmaxf(lg[0], lg[1]), fmaxf(lg[2], lg[3]));
  float ex[4], esum = 0.f;
  #pragma unroll
  for (int e = 0; e < 4; ++e){ ex[e] = __expf(lg[e] - mx); esum += ex[e]; }
  if (tid < 4) score[n*4 + tid] = ex[tid] / esum;

  half4 o;
  #pragma unroll
  for (int j = 0; j < 4; ++j) o[j] = (_Float16)((xa[j] - mu) * rsig);
  *(half4*)(xnb + (size_t)n*DD + tid*4) = o;
}

// ---------------- kernel 2: W [K,F] fp32 -> WT [F,K] f16 --------------------
// AFFINE: WT = g[k]*W (LN gain folded along K); part[kt,f] = sum_k b[k]*W[k,f]
template<bool AFFINE>
__global__ __launch_bounds__(256) void transpose_f16_kernel(
    const float* __restrict__ W, _Float16* __restrict__ WT, int K, int F,
    const float* __restrict__ gvec, const float* __restrict__ bvec,
    float* __restrict__ part)
{
  __shared__ float t[64][65];
  __shared__ float red2[16][64];
  int k0 = blockIdx.x * 64, f0 = blockIdx.y * 64;
  int tid = threadIdx.x;
  int r = tid >> 4, c4 = (tid & 15) * 4;
  float pf[4] = {0.f, 0.f, 0.f, 0.f};
  #pragma unroll
  for (int i = 0; i < 4; ++i){
    int k = k0 + i*16 + r;
    float4 v = *(const float4*)(W + (size_t)k*F + f0 + c4);
    if constexpr (AFFINE){
      float bk = bvec[k];
      pf[0] += bk*v.x; pf[1] += bk*v.y; pf[2] += bk*v.z; pf[3] += bk*v.w;
      float gk = gvec[k];
      v.x *= gk; v.y *= gk; v.z *= gk; v.w *= gk;
    }
    t[i*16 + r][c4+0] = v.x; t[i*16 + r][c4+1] = v.y;
    t[i*16 + r][c4+2] = v.z; t[i*16 + r][c4+3] = v.w;
  }
  if constexpr (AFFINE){
    #pragma unroll
    for (int j = 0; j < 4; ++j) red2[r][c4+j] = pf[j];
  }
  __syncthreads();
  int f = tid >> 2, seg = tid & 3;
  half8 o0, o1;
  #pragma unroll
  for (int j = 0; j < 8; ++j){
    o0[j] = (_Float16)t[seg*16 + j][f];
    o1[j] = (_Float16)t[seg*16 + 8 + j][f];
  }
  _Float16* dst = WT + (size_t)(f0 + f)*K + k0 + seg*16;
  *(half8*)dst = o0;
  *(half8*)(dst + 8) = o1;
  if constexpr (AFFINE){
    if (tid < 64){
      float s = 0.f;
      #pragma unroll
      for (int rr = 0; rr < 16; ++rr) s += red2[rr][tid];
      part[(size_t)blockIdx.x * F + f0 + tid] = s;
    }
  }
}

// ---------------- BB1[e,f] = b_attn[e,f] + sum_i part[e*16+i, f] ------------
__global__ __launch_bounds__(256) void bb1_kernel(
    const float* __restrict__ b_attn, const float* __restrict__ part,
    float* __restrict__ BB1)
{
  int idx = blockIdx.x*256 + threadIdx.x;   // e*FF1 + f
  int e = idx / FF1, f = idx - e*FF1;
  float s = b_attn[idx];
  #pragma unroll
  for (int i = 0; i < 16; ++i)
    s += part[(size_t)(e*16 + i)*FF1 + f];
  BB1[idx] = s;
}

// ---------------- GEMM1: qkv[4096,3072] = sum_e s_e*(xn @ W1g_e) + bias -----
// 256x192 tile, BK=64, 8 waves (4M x 2N), dbuf, counted vmcnt, 3-phase,
// setprio (T5), XOR-swizzle (T2). 32x32x16 MFMA: per-wave 2x3 frags of 32x32.
// score via TELESCOPING acc rescale at expert boundaries; final s3 in epilogue.
#define G1_BM 256
#define G1_BN 192
#define G1_BK 64
#define G1_T  (KK2/G1_BK)            // 64 K-tiles (16 per expert)
#define G1_ABUF (G1_BM*G1_BK)        // 16384 f16
#define G1_BBUF (G1_BN*G1_BK)        // 12288 f16
#define G1_BUFSZ (G1_ABUF+G1_BBUF)   // 28672 f16 per buffer

__global__ __launch_bounds__(512, 2) void gemm1_kernel(
    const _Float16* __restrict__ XN, const _Float16* __restrict__ BT,
    const float* __restrict__ score, const float* __restrict__ bias,
    _Float16* __restrict__ C)
{
  __shared__ _Float16 smem[2*G1_BUFSZ];   // 112 KiB
  int tid = threadIdx.x;
  int lane = tid & 63, wid = tid >> 6;
  int q2 = lane & 31, g2 = lane >> 5;
  int wr = wid >> 1, wc = wid & 1;
  int xo = (lane & 7) << 3;
  int bid = blockIdx.x;
  int xcd = bid & 7, li = bid >> 3;
  int m0 = (li >> 1) * G1_BM;
  int n0 = (xcd*2 + (li & 1)) * G1_BN;

  int arow[2], brow[3];
  #pragma unroll
  for (int mf = 0; mf < 2; ++mf) arow[mf] = (wr*64 + mf*32 + q2)*64;
  #pragma unroll
  for (int nf = 0; nf < 3; ++nf) brow[nf] = G1_ABUF + (wc*96 + nf*32 + q2)*64;
  int koff[4];
  #pragma unroll
  for (int kk = 0; kk < 4; ++kk) koff[kk] = (kk*16 + g2*8) ^ xo;

  auto stageA = [&](int t, int buf, int h){
    const int d0 = (t & 15) * G1_BK;
    _Float16* sA = smem + buf*G1_BUFSZ;
    #pragma unroll
    for (int ld = 0; ld < 2; ++ld){
      int l = h*2 + ld;
      int c = l*512 + tid;
      int row = c >> 3;
      int seg = (c & 7) ^ (row & 7);     // inverse-swizzled global source
      GLOAD_LDS16(XN + (size_t)(m0 + row)*DD + d0 + seg*8,
                  sA + (l*512 + wid*64)*8);
    }
  };
  auto stageB = [&](int t, int buf){
    const int k0 = t * G1_BK;
    _Float16* sB = smem + buf*G1_BUFSZ + G1_ABUF;
    #pragma unroll
    for (int ld = 0; ld < 3; ++ld){
      int c = ld*512 + tid;
      int row = c >> 3;
      int seg = (c & 7) ^ (row & 7);
      GLOAD_LDS16(BT + (size_t)(n0 + row)*KK2 + k0 + seg*8,
                  sB + (ld*512 + wid*64)*8);
    }
  };

  f32x16 acc[2][3] = {};
  half8 af0[4], af1[4], bf[3][4];

  stageA(0, 0, 0); stageA(0, 0, 1); stageB(0, 0);

  for (int t = 0; t < G1_T-1; ++t){
    if (t && (t & 15) == 0){              // expert boundary: acc *= s_{e-1}/s_e
      int e = t >> 4;
      #pragma unroll
      for (int mf = 0; mf < 2; ++mf)
        #pragma unroll
        for (int reg = 0; reg < 16; ++reg){
          int row32 = (reg & 3) + 8*(reg >> 2) + 4*g2;
          int gm = m0 + wr*64 + mf*32 + row32;
          float2 s2 = *(const float2*)(score + gm*4 + (e-1));
          float ratio = s2.x / s2.y;
          acc[mf][0][reg] *= ratio;
          acc[mf][1][reg] *= ratio;
          acc[mf][2][reg] *= ratio;
        }
    }
    int buf = t & 1, nxt = buf ^ 1;
    const _Float16* base = smem + buf*G1_BUFSZ;
    stageA(t+1, nxt, 0);                           // 2 loads -> 9 outstanding
    asm volatile("s_waitcnt vmcnt(2)" ::: "memory");  // tile t (oldest 7) landed
    SBAR();                                        // rendezvous: buf(t) ready
    // ---- ph0: mf0 x nf{0,1} ----
    #pragma unroll
    for (int kk = 0; kk < 4; ++kk){
      af0[kk]  = *(const half8*)(base + arow[0] + koff[kk]);
      bf[0][kk] = *(const half8*)(base + brow[0] + koff[kk]);
      bf[1][kk] = *(const half8*)(base + brow[1] + koff[kk]);
    }
    stageA(t+1, nxt, 1);
    __builtin_amdgcn_s_setprio(1);
    #pragma unroll
    for (int kk = 0; kk < 4; ++kk){
      acc[0][0] = mfma32(af0[kk], bf[0][kk], acc[0][0]);
      acc[0][1] = mfma32(af0[kk], bf[1][kk], acc[0][1]);
    }
    __builtin_amdgcn_s_setprio(0);
    SBAR();
    // ---- ph1: mf0 x nf2, mf1 x nf0 ----
    #pragma unroll
    for (int kk = 0; kk < 4; ++kk){
      bf[2][kk] = *(const half8*)(base + brow[2] + koff[kk]);
      af1[kk]   = *(const half8*)(base + arow[1] + koff[kk]);
    }
    stageB(t+1, nxt);
    __builtin_amdgcn_s_setprio(1);
    #pragma unroll
    for (int kk = 0; kk < 4; ++kk){
      acc[0][2] = mfma32(af0[kk], bf[2][kk], acc[0][2]);
      acc[1][0] = mfma32(af1[kk], bf[0][kk], acc[1][0]);
    }
    __builtin_amdgcn_s_setprio(0);
    SBAR();                                        // last LDS reads of buf done
    // ---- ph2: mf1 x nf{1,2} (regs only; overlaps next tile's top) ----
    __builtin_amdgcn_s_setprio(1);
    #pragma unroll
    for (int kk = 0; kk < 4; ++kk){
      acc[1][1] = mfma32(af1[kk], bf[1][kk], acc[1][1]);
      acc[1][2] = mfma32(af1[kk], bf[2][kk], acc[1][2]);
    }
    __builtin_amdgcn_s_setprio(0);
  }
  // ---- last tile (expert 3, no boundary) ----
  {
    const _Float16* base = smem + ((G1_T-1) & 1)*G1_BUFSZ;
    asm volatile("s_waitcnt vmcnt(0)" ::: "memory");
    SBAR();
    #pragma unroll
    for (int kk = 0; kk < 4; ++kk){
      af0[kk] = *(const half8*)(base + arow[0] + koff[kk]);
      af1[kk] = *(const half8*)(base + arow[1] + koff[kk]);
      #pragma unroll
      for (int nf = 0; nf < 3; ++nf)
        bf[nf][kk] = *(const half8*)(base + brow[nf] + koff[kk]);
    }
    #pragma unroll
    for (int kk = 0; kk < 4; ++kk)
      #pragma unroll
      for (int nf = 0; nf < 3; ++nf){
        acc[0][nf] = mfma32(af0[kk], bf[nf][kk], acc[0][nf]);
        acc[1][nf] = mfma32(af1[kk], bf[nf][kk], acc[1][nf]);
      }
  }

  // epilogue: v = acc*s3 + sum_e score[m,e]*BB1[e,n], f16 store
  float bv[3][4];
  #pragma unroll
  for (int nf = 0; nf < 3; ++nf){
    int gn = n0 + wc*96 + nf*32 + q2;
    #pragma unroll
    for (int e = 0; e < 4; ++e) bv[nf][e] = bias[e*FF1 + gn];
  }
  #pragma unroll
  for (int mf = 0; mf < 2; ++mf){
    #pragma unroll
    for (int reg = 0; reg < 16; ++reg){
      int row32 = (reg & 3) + 8*(reg >> 2) + 4*g2;
      int gm = m0 + wr*64 + mf*32 + row32;
      float4 sc = *(const float4*)(score + gm*4);
      #pragma unroll
      for (int nf = 0; nf < 3; ++nf){
        int gn = n0 + wc*96 + nf*32 + q2;
        float v = acc[mf][nf][reg]*sc.w
                + sc.x*bv[nf][0] + sc.y*bv[nf][1] + sc.z*bv[nf][2] + sc.w*bv[nf][3];
        C[(size_t)gm*FF1 + gn] = (_Float16)v;
      }
    }
  }
}

// ---------------- GEMM2: out = sum_e s_e*(ctx @ W2_e) + bias ----------------
// 128x128 tile, BK=64, 8 waves (2M x 4N), dbuf, counted vmcnt(4), 32x32x16
// MFMA (2x1 frags/wave), per-expert acc split, 2-phase compute.
#define G2_BK 64
#define G2_ABUF (128*G2_BK)
#define G2_BUFSZ (2*G2_ABUF)         // A+B per buffer = 32 KiB

__global__ __launch_bounds__(512) void gemm2_kernel(
    const _Float16* __restrict__ CTX, const _Float16* __restrict__ BT,
    const float* __restrict__ score, const float* __restrict__ bias,
    float* __restrict__ Cout)
{
  __shared__ _Float16 smem[2*G2_BUFSZ];   // 64 KiB
  int tid = threadIdx.x;
  int lane = tid & 63, wid = tid >> 6;
  int q2 = lane & 31, g2 = lane >> 5;
  int wr = wid >> 2, wc = wid & 3;     // 2M x 4N
  int xo = (lane & 7) << 3;
  int bid = blockIdx.x;
  int xcd = bid >> 5, idx = bid & 31;
  int m0 = (xcd*4 + (idx >> 3)) * 128;
  int n0 = (idx & 7) * 128;

  int arow[2], brow;
  #pragma unroll
  for (int mf = 0; mf < 2; ++mf) arow[mf] = (wr*64 + mf*32 + q2)*64;
  brow = G2_ABUF + (wc*32 + q2)*64;
  int koff[4];
  #pragma unroll
  for (int kk = 0; kk < 4; ++kk) koff[kk] = (kk*16 + g2*8) ^ xo;

  auto stageA = [&](int t, int buf){
    const int d0 = (t & 15) * G2_BK;
    _Float16* sA = smem + buf*G2_BUFSZ;
    #pragma unroll
    for (int ld = 0; ld < 2; ++ld){
      int c = ld*512 + tid;
      int row = c >> 3;
      int seg = (c & 7) ^ (row & 7);
      GLOAD_LDS16(CTX + (size_t)(m0 + row)*DD + d0 + seg*8,
                  sA + (ld*512 + wid*64)*8);
    }
  };
  auto stageB = [&](int t, int buf){
    const int k0 = t * G2_BK;
    _Float16* sB = smem + buf*G2_BUFSZ + G2_ABUF;
    #pragma unroll
    for (int ld = 0; ld < 2; ++ld){
      int c = ld*512 + tid;
      int row = c >> 3;
      int seg = (c & 7) ^ (row & 7);
      GLOAD_LDS16(BT + (size_t)(n0 + row)*KK2 + k0 + seg*8,
                  sB + (ld*512 + wid*64)*8);
    }
  };

  f32x16 accp[2] = {}, acco[2] = {};

  auto merge = [&](int e){
    #pragma unroll
    for (int m = 0; m < 2; ++m)
      #pragma unroll
      for (int reg = 0; reg < 16; ++reg){
        int row32 = (reg & 3) + 8*(reg >> 2) + 4*g2;
        int gm = m0 + wr*64 + m*32 + row32;
        float s = score[(size_t)gm*4 + e];
        acco[m][reg] += s*accp[m][reg];
        accp[m][reg] = 0.f;
      }
  };

  stageA(0, 0); stageB(0, 0);
  for (int t = 0; t < KK2/G2_BK - 1; ++t){
    int buf = t & 1, nxt = buf ^ 1;
    const _Float16* base = smem + buf*G2_BUFSZ;
    stageA(t+1, nxt);
    asm volatile("s_waitcnt vmcnt(2)" ::: "memory");  // tile t (oldest 4) landed
    SBAR();
    // ---- ph0: all reads, stage B, kk{0,1} ----
    half8 af[2][4], bfr[4];
    #pragma unroll
    for (int kk = 0; kk < 4; ++kk){
      af[0][kk] = *(const half8*)(base + arow[0] + koff[kk]);
      af[1][kk] = *(const half8*)(base + arow[1] + koff[kk]);
      bfr[kk]   = *(const half8*)(base + brow + koff[kk]);
    }
    stageB(t+1, nxt);
    __builtin_amdgcn_s_setprio(1);
    #pragma unroll
    for (int kk = 0; kk < 2; ++kk){
      accp[0] = mfma32(af[0][kk], bfr[kk], accp[0]);
      accp[1] = mfma32(af[1][kk], bfr[kk], accp[1]);
    }
    __builtin_amdgcn_s_setprio(0);
    SBAR();                                           // reads done -> restage ok
    // ---- ph1: kk{2,3} (regs only; overlaps next top) ----
    __builtin_amdgcn_s_setprio(1);
    #pragma unroll
    for (int kk = 2; kk < 4; ++kk){
      accp[0] = mfma32(af[0][kk], bfr[kk], accp[0]);
      accp[1] = mfma32(af[1][kk], bfr[kk], accp[1]);
    }
    __builtin_amdgcn_s_setprio(0);
    if ((t & 15) == 15) merge(t >> 4);                // expert boundary
  }
  {
    const _Float16* base = smem + ((KK2/G2_BK - 1) & 1)*G2_BUFSZ;
    asm volatile("s_waitcnt vmcnt(0)" ::: "memory");
    SBAR();
    half8 af[2][4], bfr[4];
    #pragma unroll
    for (int kk = 0; kk < 4; ++kk){
      af[0][kk] = *(const half8*)(base + arow[0] + koff[kk]);
      af[1][kk] = *(const half8*)(base + arow[1] + koff[kk]);
      bfr[kk]   = *(const half8*)(base + brow + koff[kk]);
    }
    #pragma unroll
    for (int kk = 0; kk < 4; ++kk){
      accp[0] = mfma32(af[0][kk], bfr[kk], accp[0]);
      accp[1] = mfma32(af[1][kk], bfr[kk], accp[1]);
    }
    merge(3);
  }

  #pragma unroll
  for (int m = 0; m < 2; ++m){
    #pragma unroll
    for (int reg = 0; reg < 16; ++reg){
      int row32 = (reg & 3) + 8*(reg >> 2) + 4*g2;
      int gm = m0 + wr*64 + m*32 + row32;
      float4 sc = *(const float4*)(score + gm*4);
      int gn = n0 + wc*32 + q2;
      float v = acco[m][reg]
              + sc.x*bias[gn] + sc.y*bias[DD+gn]
              + sc.z*bias[2*DD+gn] + sc.w*bias[3*DD+gn];
      Cout[(size_t)gm*DD + gn] = v;
    }
  }
}

// ---------------- kernel 4: causal flash attention --------------------------
__global__ __launch_bounds__(256) void attn_kernel(
    const _Float16* __restrict__ qkv, _Float16* __restrict__ ctx)
{
  __shared__ _Float16 lsK[64*64];      // [key][hd], swizzled
  __shared__ _Float16 lsV[64*64];      // [hd][key], swizzled (transposed)
  __shared__ _Float16 lsP[4][16*64];   // per-wave P [qrow][key], swizzled
  int bh = blockIdx.x, qt = blockIdx.y;
  int b = bh >> 4, h = bh & 15;
  int tid = threadIdx.x, lane = tid & 63, wid = tid >> 6;
  int q = lane & 15, g = lane >> 4;
  int xo = (q & 7) << 3;
  int qrow0 = qt*64 + wid*16;

  half8 qf[2];
  #pragma unroll
  for (int kk = 0; kk < 2; ++kk)
    qf[kk] = *(const half8*)(qkv + ((size_t)b*SS + qrow0 + q)*FF1 + h*HDD + kk*32 + g*8);

  f32x4 o[4] = {};
  float mrow = -1e30f, lsum = 0.f;     // stats for qrow = q (log2 domain)
  const float SC2 = 0.18033688011112042f;  // log2(e)/8
  int qglob = qrow0 + q;

  for (int kt = 0; kt <= qt; ++kt){
    __syncthreads();                   // prev-iter LDS reads done
    size_t kvrow = (size_t)b*SS + kt*64;
    #pragma unroll
    for (int i = 0; i < 2; ++i){       // stage K (pre-swizzled source)
      int c = i*256 + tid;
      int row = c >> 3, seg = (c & 7) ^ (row & 7);
      GLOAD_LDS16(qkv + (kvrow + row)*FF1 + DD + h*HDD + seg*8,
                  lsK + (size_t)(i*256 + wid*64)*8);
    }
    #pragma unroll
    for (int i = 0; i < 2; ++i){       // stage V transposed + swizzled
      int p = wid*2 + i;
      half8 v = *(const half8*)(qkv + (kvrow + lane)*FF1 + 2*DD + h*HDD + p*8);
      #pragma unroll
      for (int j = 0; j < 8; ++j){
        int hd = p*8 + j;
        lsV[hd*64 + (lane ^ ((hd & 7) << 3))] = v[j];
      }
    }
    __syncthreads();

    f32x4 st[4] = {};                  // S^T frags: row=key(g*4+r,+16i), col=qrow(q)
    #pragma unroll
    for (int i = 0; i < 4; ++i){
      #pragma unroll
      for (int kk = 0; kk < 2; ++kk){
        half8 kf = *(const half8*)(lsK + (i*16 + q)*64 + ((kk*32 + g*8) ^ xo));
        st[i] = mfma16(kf, qf[kk], st[i]);
      }
    }
    float pvv[16]; float tm = -1e30f;
    #pragma unroll
    for (int i = 0; i < 4; ++i)
      #pragma unroll
      for (int r = 0; r < 4; ++r){
        int kglob = kt*64 + i*16 + g*4 + r;
        float sv = (kglob <= qglob) ? st[i][r]*SC2 : -1e30f;
        pvv[i*4+r] = sv; tm = fmaxf(tm, sv);
      }
    tm = fmaxf(tm, __shfl_xor(tm, 16, 64));
    tm = fmaxf(tm, __shfl_xor(tm, 32, 64));
    float mnew  = fmaxf(mrow, tm);
    float alpha = exp2f(mrow - mnew);
    mrow = mnew;
    float psum = 0.f;
    _Float16 pb[16];
    #pragma unroll
    for (int i = 0; i < 16; ++i){
      float p = exp2f(pvv[i] - mnew);
      psum += p; pb[i] = (_Float16)p;
    }
    lsum = lsum*alpha + psum;
    float af4[4];
    #pragma unroll
    for (int r = 0; r < 4; ++r) af4[r] = __shfl(alpha, g*4 + r, 64);
    #pragma unroll
    for (int n = 0; n < 4; ++n)
      #pragma unroll
      for (int r = 0; r < 4; ++r) o[n][r] *= af4[r];
    #pragma unroll
    for (int i = 0; i < 4; ++i){       // P -> wave-private LDS (swizzled)
      half4 w4;
      w4[0]=pb[i*4+0]; w4[1]=pb[i*4+1]; w4[2]=pb[i*4+2]; w4[3]=pb[i*4+3];
      *(half4*)(&lsP[wid][q*64 + ((i*16 + g*4) ^ xo)]) = w4;
    }
    #pragma unroll
    for (int kk = 0; kk < 2; ++kk){    // O += P * V
      half8 pf = *(const half8*)(&lsP[wid][q*64 + ((kk*32 + g*8) ^ xo)]);
      #pragma unroll
      for (int n = 0; n < 4; ++n){
        half8 vf = *(const half8*)(&lsV[(n*16 + q)*64 + ((kk*32 + g*8) ^ xo)]);
        o[n] = mfma16(pf, vf, o[n]);
      }
    }
  }
  float lt = lsum + __shfl_xor(lsum, 16, 64);
  lt = lt + __shfl_xor(lt, 32, 64);
  float rinv = 1.f / lt;
  #pragma unroll
  for (int r = 0; r < 4; ++r){
    float ri = __shfl(rinv, g*4 + r, 64);
    int qg = qt*64 + wid*16 + g*4 + r;
    _Float16* obase = ctx + ((size_t)b*SS + qg)*DD + h*HDD;
    #pragma unroll
    for (int n = 0; n < 4; ++n)
      obase[n*16 + q] = (_Float16)(o[n][r] * ri);
  }
}

// ---------------------------------------------------------------------------
extern "C" void kernel_launch(void* const* d_in, const int* in_sizes, int n_in,
                              void* d_out, int out_size, void* d_ws, size_t ws_size,
                              hipStream_t stream)
{
  const float* x      = (const float*)d_in[0];
  const float* Wr     = (const float*)d_in[1];
  const float* br     = (const float*)d_in[2];
  const float* ln_g   = (const float*)d_in[3];
  const float* ln_b   = (const float*)d_in[4];
  const float* W_attn = (const float*)d_in[5];
  const float* b_attn = (const float*)d_in[6];
  const float* W_proj = (const float*)d_in[7];
  const float* b_proj = (const float*)d_in[8];
  (void)in_sizes; (void)n_in; (void)out_size; (void)ws_size;

  char* ws = (char*)d_ws;
  size_t off = 0;
  auto alloc = [&](size_t bytes) -> void* {
    void* p = ws + off; off += (bytes + 255) & ~(size_t)255; return p;
  };
  _Float16* W1gT  = (_Float16*)alloc((size_t)FF1*KK2*2);   // 25.2 MB (g folded)
  _Float16* W2T   = (_Float16*)alloc((size_t)DD*KK2*2);    //  8.4 MB
  float*    score = (float*)   alloc((size_t)NN*4*4);      // 64 KB
  _Float16* xn16  = (_Float16*)alloc((size_t)NN*DD*2);     //  8.4 MB
  _Float16* qkv   = (_Float16*)alloc((size_t)NN*FF1*2);    // 25.2 MB
  _Float16* ctx   = (_Float16*)alloc((size_t)NN*DD*2);     //  8.4 MB
  float*    part  = (float*)   alloc((size_t)(KK2/64)*FF1*4); // 786 KB
  float*    BB1   = (float*)   alloc((size_t)EE*FF1*4);    // 48 KB

  hipLaunchKernelGGL((transpose_f16_kernel<true>), dim3(KK2/64, FF1/64), dim3(256), 0, stream,
                     W_attn, W1gT, KK2, FF1, ln_g, ln_b, part);
  hipLaunchKernelGGL((transpose_f16_kernel<false>), dim3(KK2/64, DD/64), dim3(256), 0, stream,
                     W_proj, W2T, KK2, DD, nullptr, nullptr, nullptr);
  hipLaunchKernelGGL(bb1_kernel, dim3(EE*FF1/256), dim3(256), 0, stream,
                     b_attn, part, BB1);
  hipLaunchKernelGGL(prep_kernel, dim3(NN), dim3(256), 0, stream,
                     x, Wr, br, score, xn16);
  hipLaunchKernelGGL(gemm1_kernel, dim3(256), dim3(512), 0, stream,
                     xn16, W1gT, score, BB1, qkv);
  hipLaunchKernelGGL(attn_kernel, dim3(NB*HH, SS/64), dim3(256), 0, stream,
                     qkv, ctx);
  hipLaunchKernelGGL(gemm2_kernel, dim3(256), dim3(512), 0, stream,
                     ctx, W2T, score, b_proj, (float*)d_out);
}

// Round 7
// 206.751 us; speedup vs baseline: 1.1257x; 1.1257x over previous
//
#include <hip/hip_runtime.h>
#include <stdint.h>

#define NB 4
#define SS 1024
#define DD 1024
#define EE 4
#define HH 16
#define HDD 64
#define NN (NB*SS)      // 4096 tokens
#define KK2 (EE*DD)     // 4096 expanded K
#define FF1 (3*DD)      // 3072

typedef __attribute__((ext_vector_type(4))) float f32x4;
typedef __attribute__((ext_vector_type(8))) _Float16 half8;
typedef __attribute__((ext_vector_type(4))) _Float16 half4;

static __device__ __forceinline__ f32x4 mfma16(half8 a, half8 b, f32x4 c){
  return __builtin_amdgcn_mfma_f32_16x16x32_f16(a, b, c, 0, 0, 0);
}

// async global->LDS, 16B per lane; LDS dest = wave-uniform base + lane*16
#define GLOAD_LDS16(gp, lp) __builtin_amdgcn_global_load_lds( \
    (const unsigned int __attribute__((address_space(1)))*)(uintptr_t)(gp), \
    (unsigned int __attribute__((address_space(3)))*)(uintptr_t)(lp), 16, 0, 0)

#define SBAR() do { asm volatile("" ::: "memory"); \
                    __builtin_amdgcn_s_barrier(); \
                    asm volatile("" ::: "memory"); } while(0)

// ---------------- kernel 1: router softmax + LN stats + xn (f16) -----------
__global__ __launch_bounds__(256) void prep_kernel(
    const float* __restrict__ x, const float* __restrict__ Wr,
    const float* __restrict__ br, float* __restrict__ score,
    float* __restrict__ ratios, _Float16* __restrict__ xnb)
{
  int n = blockIdx.x;
  int tid = threadIdx.x;
  float4 xv = ((const float4*)(x + (size_t)n*DD))[tid];   // d = tid*4..+3
  float xa[4] = {xv.x, xv.y, xv.z, xv.w};
  float vals[6];
  vals[0] = xa[0]+xa[1]+xa[2]+xa[3];
  vals[1] = xa[0]*xa[0]+xa[1]*xa[1]+xa[2]*xa[2]+xa[3]*xa[3];
  vals[2] = vals[3] = vals[4] = vals[5] = 0.f;
  #pragma unroll
  for (int j = 0; j < 4; ++j){
    float4 w = ((const float4*)Wr)[tid*4 + j];  // Wr row d = 4 expert weights
    vals[2] += xa[j]*w.x; vals[3] += xa[j]*w.y;
    vals[4] += xa[j]*w.z; vals[5] += xa[j]*w.w;
  }
  #pragma unroll
  for (int off = 32; off >= 1; off >>= 1)
    #pragma unroll
    for (int i = 0; i < 6; ++i)
      vals[i] += __shfl_xor(vals[i], off, 64);
  __shared__ float red[4][6];
  int wid = tid >> 6;
  if ((tid & 63) == 0){
    #pragma unroll
    for (int i = 0; i < 6; ++i) red[wid][i] = vals[i];
  }
  __syncthreads();
  float tot[6];
  #pragma unroll
  for (int i = 0; i < 6; ++i)
    tot[i] = red[0][i] + red[1][i] + red[2][i] + red[3][i];

  float mu   = tot[0] * (1.f/DD);
  float var  = tot[1] * (1.f/DD) - mu*mu;
  float rsig = rsqrtf(var + 1e-5f);
  float lg[4];
  #pragma unroll
  for (int e = 0; e < 4; ++e) lg[e] = tot[2+e] + br[e];
  float mx = fmaxf(fmaxf(lg[0], lg[1]), fmaxf(lg[2], lg[3]));
  float ex[4], esum = 0.f;
  #pragma unroll
  for (int e = 0; e < 4; ++e){ ex[e] = __expf(lg[e] - mx); esum += ex[e]; }
  if (tid < 4){
    score[n*4 + tid] = ex[tid] / esum;
    ratios[n*4 + tid] = (tid > 0) ? (ex[tid-1] / ex[tid]) : 0.f;
  }

  half4 o;
  #pragma unroll
  for (int j = 0; j < 4; ++j) o[j] = (_Float16)((xa[j] - mu) * rsig);
  *(half4*)(xnb + (size_t)n*DD + tid*4) = o;
}

// ---------------- kernel 2: W [K,F] fp32 -> WT [F,K] f16 --------------------
// AFFINE: WT = g[k]*W (LN gain folded along K); part[kt,f] = sum_k b[k]*W[k,f]
template<bool AFFINE>
__global__ __launch_bounds__(256) void transpose_f16_kernel(
    const float* __restrict__ W, _Float16* __restrict__ WT, int K, int F,
    const float* __restrict__ gvec, const float* __restrict__ bvec,
    float* __restrict__ part)
{
  __shared__ float t[64][65];
  __shared__ float red2[16][64];
  int k0 = blockIdx.x * 64, f0 = blockIdx.y * 64;
  int tid = threadIdx.x;
  int r = tid >> 4, c4 = (tid & 15) * 4;
  float pf[4] = {0.f, 0.f, 0.f, 0.f};
  #pragma unroll
  for (int i = 0; i < 4; ++i){
    int k = k0 + i*16 + r;
    float4 v = *(const float4*)(W + (size_t)k*F + f0 + c4);
    if constexpr (AFFINE){
      float bk = bvec[k];
      pf[0] += bk*v.x; pf[1] += bk*v.y; pf[2] += bk*v.z; pf[3] += bk*v.w;
      float gk = gvec[k];
      v.x *= gk; v.y *= gk; v.z *= gk; v.w *= gk;
    }
    t[i*16 + r][c4+0] = v.x; t[i*16 + r][c4+1] = v.y;
    t[i*16 + r][c4+2] = v.z; t[i*16 + r][c4+3] = v.w;
  }
  if constexpr (AFFINE){
    #pragma unroll
    for (int j = 0; j < 4; ++j) red2[r][c4+j] = pf[j];
  }
  __syncthreads();
  int f = tid >> 2, seg = tid & 3;
  half8 o0, o1;
  #pragma unroll
  for (int j = 0; j < 8; ++j){
    o0[j] = (_Float16)t[seg*16 + j][f];
    o1[j] = (_Float16)t[seg*16 + 8 + j][f];
  }
  _Float16* dst = WT + (size_t)(f0 + f)*K + k0 + seg*16;
  *(half8*)dst = o0;
  *(half8*)(dst + 8) = o1;
  if constexpr (AFFINE){
    if (tid < 64){
      float s = 0.f;
      #pragma unroll
      for (int rr = 0; rr < 16; ++rr) s += red2[rr][tid];
      part[(size_t)blockIdx.x * F + f0 + tid] = s;
    }
  }
}

// ---------------- BB1[e,f] = b_attn[e,f] + sum_i part[e*16+i, f] ------------
__global__ __launch_bounds__(256) void bb1_kernel(
    const float* __restrict__ b_attn, const float* __restrict__ part,
    float* __restrict__ BB1)
{
  int idx = blockIdx.x*256 + threadIdx.x;   // e*FF1 + f
  int e = idx / FF1, f = idx - e*FF1;
  float s = b_attn[idx];
  #pragma unroll
  for (int i = 0; i < 16; ++i)
    s += part[(size_t)(e*16 + i)*FF1 + f];
  BB1[idx] = s;
}

// ---------------- GEMM1: qkv[4096,3072] = sum_e s_e*(xn @ W1g_e) + bias -----
// 256x192 tile, BK=64, 8 waves (4M x 2N), dbuf, counted vmcnt, 4-phase (T3),
// setprio (T5), XOR-swizzle (T2). 16x16x32 MFMA. score applied by TELESCOPING
// acc rescale at expert boundaries (ratio table, no divides); s3 in epilogue.
#define G1_BM 256
#define G1_BN 192
#define G1_BK 64
#define G1_T  (KK2/G1_BK)            // 64 K-tiles (16 per expert)
#define G1_ABUF (G1_BM*G1_BK)        // 16384 f16
#define G1_BBUF (G1_BN*G1_BK)        // 12288 f16
#define G1_BUFSZ (G1_ABUF+G1_BBUF)   // 28672 f16 per buffer

__global__ __launch_bounds__(512, 2) void gemm1_kernel(
    const _Float16* __restrict__ XN, const _Float16* __restrict__ BT,
    const float* __restrict__ score, const float* __restrict__ ratios,
    const float* __restrict__ bias, _Float16* __restrict__ C)
{
  __shared__ _Float16 smem[2*G1_BUFSZ];   // 112 KiB
  int tid = threadIdx.x;
  int lane = tid & 63, wid = tid >> 6;
  int q = lane & 15, g = lane >> 4;
  int wr = wid >> 1, wc = wid & 1;
  int xo = (q & 7) << 3;
  int bid = blockIdx.x;
  int xcd = bid & 7, li = bid >> 3;
  int m0 = (li >> 1) * G1_BM;
  int n0 = (xcd*2 + (li & 1)) * G1_BN;

  int arow[4], brow[6];
  #pragma unroll
  for (int mf = 0; mf < 4; ++mf) arow[mf] = (wr*64 + mf*16 + q)*64;
  #pragma unroll
  for (int nf = 0; nf < 6; ++nf) brow[nf] = G1_ABUF + (wc*96 + nf*16 + q)*64;
  int soff[2] = { (g*8) ^ xo, (32 + g*8) ^ xo };

  auto stageA = [&](int t, int buf, int h){
    const int d0 = (t & 15) * G1_BK;
    _Float16* sA = smem + buf*G1_BUFSZ;
    #pragma unroll
    for (int ld = 0; ld < 2; ++ld){
      int l = h*2 + ld;
      int c = l*512 + tid;
      int row = c >> 3;
      int seg = (c & 7) ^ (row & 7);     // inverse-swizzled global source
      GLOAD_LDS16(XN + (size_t)(m0 + row)*DD + d0 + seg*8,
                  sA + (l*512 + wid*64)*8);
    }
  };
  auto stageB = [&](int t, int buf){
    const int k0 = t * G1_BK;
    _Float16* sB = smem + buf*G1_BUFSZ + G1_ABUF;
    #pragma unroll
    for (int ld = 0; ld < 3; ++ld){
      int c = ld*512 + tid;
      int row = c >> 3;
      int seg = (c & 7) ^ (row & 7);
      GLOAD_LDS16(BT + (size_t)(n0 + row)*KK2 + k0 + seg*8,
                  sB + (ld*512 + wid*64)*8);
    }
  };

  f32x4 acc[4][6] = {};
  half8 af0[2][2], af2[2][2], bf[6][2];

  stageA(0, 0, 0); stageA(0, 0, 1); stageB(0, 0);

  for (int t = 0; t < G1_T-1; ++t){
    if (t && (t & 15) == 0){              // expert boundary: acc *= s_{e-1}/s_e
      int e = t >> 4;
      #pragma unroll
      for (int mf = 0; mf < 4; ++mf)
        #pragma unroll
        for (int r = 0; r < 4; ++r){
          int gm = m0 + wr*64 + mf*16 + g*4 + r;
          float ratio = ratios[gm*4 + e];
          #pragma unroll
          for (int nf = 0; nf < 6; ++nf)
            acc[mf][nf][r] *= ratio;
        }
    }
    int buf = t & 1, nxt = buf ^ 1;
    const _Float16* base = smem + buf*G1_BUFSZ;
    stageA(t+1, nxt, 0);                           // 2 loads -> 9 outstanding
    asm volatile("s_waitcnt vmcnt(2)" ::: "memory");  // tile t (oldest 7) landed
    SBAR();                                        // rendezvous: buf(t) ready
    // ---- ph0: m01 x n012 ----
    #pragma unroll
    for (int m = 0; m < 2; ++m)
      #pragma unroll
      for (int k = 0; k < 2; ++k)
        af0[m][k] = *(const half8*)(base + arow[m] + soff[k]);
    #pragma unroll
    for (int n = 0; n < 3; ++n)
      #pragma unroll
      for (int k = 0; k < 2; ++k)
        bf[n][k] = *(const half8*)(base + brow[n] + soff[k]);
    stageA(t+1, nxt, 1);
    __builtin_amdgcn_s_setprio(1);
    #pragma unroll
    for (int k = 0; k < 2; ++k)
      #pragma unroll
      for (int m = 0; m < 2; ++m)
        #pragma unroll
        for (int n = 0; n < 3; ++n)
          acc[m][n] = mfma16(af0[m][k], bf[n][k], acc[m][n]);
    __builtin_amdgcn_s_setprio(0);
    SBAR();
    // ---- ph1: m01 x n345 ----
    #pragma unroll
    for (int n = 3; n < 6; ++n)
      #pragma unroll
      for (int k = 0; k < 2; ++k)
        bf[n][k] = *(const half8*)(base + brow[n] + soff[k]);
    stageB(t+1, nxt);
    __builtin_amdgcn_s_setprio(1);
    #pragma unroll
    for (int k = 0; k < 2; ++k)
      #pragma unroll
      for (int m = 0; m < 2; ++m)
        #pragma unroll
        for (int n = 3; n < 6; ++n)
          acc[m][n] = mfma16(af0[m][k], bf[n][k], acc[m][n]);
    __builtin_amdgcn_s_setprio(0);
    SBAR();
    // ---- ph2: m23 x n345 ----
    #pragma unroll
    for (int m = 0; m < 2; ++m)
      #pragma unroll
      for (int k = 0; k < 2; ++k)
        af2[m][k] = *(const half8*)(base + arow[2+m] + soff[k]);
    __builtin_amdgcn_s_setprio(1);
    #pragma unroll
    for (int k = 0; k < 2; ++k)
      #pragma unroll
      for (int m = 0; m < 2; ++m)
        #pragma unroll
        for (int n = 3; n < 6; ++n)
          acc[2+m][n] = mfma16(af2[m][k], bf[n][k], acc[2+m][n]);
    __builtin_amdgcn_s_setprio(0);
    SBAR();                                        // last LDS reads of buf done
    // ---- ph3: m23 x n012 (regs only; overlaps next tile's top) ----
    __builtin_amdgcn_s_setprio(1);
    #pragma unroll
    for (int k = 0; k < 2; ++k)
      #pragma unroll
      for (int m = 0; m < 2; ++m)
        #pragma unroll
        for (int n = 0; n < 3; ++n)
          acc[2+m][n] = mfma16(af2[m][k], bf[n][k], acc[2+m][n]);
    __builtin_amdgcn_s_setprio(0);
  }
  // ---- last tile (expert 3, no boundary) ----
  {
    const _Float16* base = smem + ((G1_T-1) & 1)*G1_BUFSZ;
    asm volatile("s_waitcnt vmcnt(0)" ::: "memory");
    SBAR();
    #pragma unroll
    for (int m = 0; m < 2; ++m)
      #pragma unroll
      for (int k = 0; k < 2; ++k){
        af0[m][k] = *(const half8*)(base + arow[m] + soff[k]);
        af2[m][k] = *(const half8*)(base + arow[2+m] + soff[k]);
      }
    #pragma unroll
    for (int n = 0; n < 6; ++n)
      #pragma unroll
      for (int k = 0; k < 2; ++k)
        bf[n][k] = *(const half8*)(base + brow[n] + soff[k]);
    #pragma unroll
    for (int k = 0; k < 2; ++k)
      #pragma unroll
      for (int m = 0; m < 2; ++m)
        #pragma unroll
        for (int n = 0; n < 6; ++n){
          acc[m][n]   = mfma16(af0[m][k], bf[n][k], acc[m][n]);
          acc[2+m][n] = mfma16(af2[m][k], bf[n][k], acc[2+m][n]);
        }
  }

  // epilogue: v = acc*s3 + sum_e score[m,e]*BB1[e,n], f16 store
  float bv[6][4];
  #pragma unroll
  for (int nf = 0; nf < 6; ++nf){
    int gn = n0 + wc*96 + nf*16 + q;
    #pragma unroll
    for (int e = 0; e < 4; ++e) bv[nf][e] = bias[e*FF1 + gn];
  }
  #pragma unroll
  for (int mf = 0; mf < 4; ++mf){
    #pragma unroll
    for (int r = 0; r < 4; ++r){
      int gm = m0 + wr*64 + mf*16 + g*4 + r;
      float4 sc = *(const float4*)(score + gm*4);
      #pragma unroll
      for (int nf = 0; nf < 6; ++nf){
        int gn = n0 + wc*96 + nf*16 + q;
        float v = acc[mf][nf][r]*sc.w
                + sc.x*bv[nf][0] + sc.y*bv[nf][1] + sc.z*bv[nf][2] + sc.w*bv[nf][3];
        C[(size_t)gm*FF1 + gn] = (_Float16)v;
      }
    }
  }
}

// ---------------- GEMM2: out = sum_e s_e*(ctx @ W2_e) + bias ----------------
// 128x128 tile, BK=64, 8 waves (2M x 4N), dbuf, counted vmcnt(4), per-expert
// accumulator split (acco += s*accp every 16 tiles). A = ctx[4096,1024].
#define G2_BK 64
#define G2_ABUF (128*G2_BK)
#define G2_BUFSZ (2*G2_ABUF)         // A+B per buffer = 32 KiB

__global__ __launch_bounds__(512) void gemm2_kernel(
    const _Float16* __restrict__ CTX, const _Float16* __restrict__ BT,
    const float* __restrict__ score, const float* __restrict__ bias,
    float* __restrict__ Cout)
{
  __shared__ _Float16 smem[2*G2_BUFSZ];   // 64 KiB
  int tid = threadIdx.x;
  int lane = tid & 63, wid = tid >> 6;
  int q = lane & 15, g = lane >> 4;
  int wr = wid >> 2, wc = wid & 3;     // 2M x 4N
  int xo = (q & 7) << 3;
  int bid = blockIdx.x;
  int xcd = bid >> 5, idx = bid & 31;
  int m0 = (xcd*4 + (idx >> 3)) * 128;
  int n0 = (idx & 7) * 128;

  int arow[4], brow[2];
  #pragma unroll
  for (int mf = 0; mf < 4; ++mf) arow[mf] = (wr*64 + mf*16 + q)*64;
  #pragma unroll
  for (int nf = 0; nf < 2; ++nf) brow[nf] = G2_ABUF + (wc*32 + nf*16 + q)*64;
  int soff[2] = { (g*8) ^ xo, (32 + g*8) ^ xo };

  auto stage = [&](int t, int buf){
    const int d0 = (t & 15) * G2_BK;
    const int k0 = t * G2_BK;
    _Float16* sA = smem + buf*G2_BUFSZ;
    _Float16* sB = sA + G2_ABUF;
    #pragma unroll
    for (int ld = 0; ld < 2; ++ld){
      int c = ld*512 + tid;
      int row = c >> 3;
      int seg = (c & 7) ^ (row & 7);
      GLOAD_LDS16(CTX + (size_t)(m0 + row)*DD + d0 + seg*8,
                  sA + (ld*512 + wid*64)*8);
    }
    #pragma unroll
    for (int ld = 0; ld < 2; ++ld){
      int c = ld*512 + tid;
      int row = c >> 3;
      int seg = (c & 7) ^ (row & 7);
      GLOAD_LDS16(BT + (size_t)(n0 + row)*KK2 + k0 + seg*8,
                  sB + (ld*512 + wid*64)*8);
    }
  };

  f32x4 accp[4][2] = {}, acco[4][2] = {};

  auto compute = [&](int buf){
    const _Float16* base = smem + buf*G2_BUFSZ;
    half8 af[4][2], bfr[2][2];
    #pragma unroll
    for (int m = 0; m < 4; ++m)
      #pragma unroll
      for (int k = 0; k < 2; ++k)
        af[m][k] = *(const half8*)(base + arow[m] + soff[k]);
    #pragma unroll
    for (int n = 0; n < 2; ++n)
      #pragma unroll
      for (int k = 0; k < 2; ++k)
        bfr[n][k] = *(const half8*)(base + brow[n] + soff[k]);
    __builtin_amdgcn_s_setprio(1);
    #pragma unroll
    for (int k = 0; k < 2; ++k)
      #pragma unroll
      for (int m = 0; m < 4; ++m)
        #pragma unroll
        for (int n = 0; n < 2; ++n)
          accp[m][n] = mfma16(af[m][k], bfr[n][k], accp[m][n]);
    __builtin_amdgcn_s_setprio(0);
  };

  auto merge = [&](int e){
    #pragma unroll
    for (int m = 0; m < 4; ++m)
      #pragma unroll
      for (int r = 0; r < 4; ++r){
        int gm = m0 + wr*64 + m*16 + g*4 + r;
        float s = score[(size_t)gm*4 + e];
        #pragma unroll
        for (int n = 0; n < 2; ++n){
          acco[m][n][r] += s*accp[m][n][r];
          accp[m][n][r] = 0.f;
        }
      }
  };

  stage(0, 0);
  for (int t = 0; t < KK2/G2_BK - 1; ++t){
    stage(t+1, (t+1)&1);
    asm volatile("s_waitcnt vmcnt(4)" ::: "memory");  // tile t landed
    SBAR();
    compute(t & 1);
    SBAR();                                           // reads done -> restage ok
    if ((t & 15) == 15) merge(t >> 4);                // expert boundary
  }
  asm volatile("s_waitcnt vmcnt(0)" ::: "memory");
  SBAR();
  compute((KK2/G2_BK - 1) & 1);
  merge(3);

  #pragma unroll
  for (int m = 0; m < 4; ++m){
    #pragma unroll
    for (int r = 0; r < 4; ++r){
      int gm = m0 + wr*64 + m*16 + g*4 + r;
      float4 sc = *(const float4*)(score + gm*4);
      #pragma unroll
      for (int n = 0; n < 2; ++n){
        int gn = n0 + wc*32 + n*16 + q;
        float v = acco[m][n][r]
                + sc.x*bias[gn] + sc.y*bias[DD+gn]
                + sc.z*bias[2*DD+gn] + sc.w*bias[3*DD+gn];
        Cout[(size_t)gm*DD + gn] = v;
      }
    }
  }
}

// ---------------- kernel 4: causal flash attention (pipelined KV) -----------
// Double-buffered K (gload_lds) and V (reg-staged), counted vmcnt(2):
// K(t+1) issued during QK^T(t); V(t) ds_write under softmax; V(t+1) issued
// before PV(t). Raw barriers + explicit lgkmcnt (no vmcnt(0) drains in loop).
__global__ __launch_bounds__(256) void attn_kernel(
    const _Float16* __restrict__ qkv, _Float16* __restrict__ ctx)
{
  __shared__ _Float16 lsK[2][64*64];   // [key][hd], swizzled
  __shared__ _Float16 lsV[2][64*64];   // [hd][key], swizzled (transposed)
  __shared__ _Float16 lsP[4][16*64];   // per-wave P [qrow][key], swizzled
  int bh = blockIdx.x, qt = blockIdx.y;
  int b = bh >> 4, h = bh & 15;
  int tid = threadIdx.x, lane = tid & 63, wid = tid >> 6;
  int q = lane & 15, g = lane >> 4;
  int xo = (q & 7) << 3;
  int qrow0 = qt*64 + wid*16;

  half8 qf[2];
  #pragma unroll
  for (int kk = 0; kk < 2; ++kk)
    qf[kk] = *(const half8*)(qkv + ((size_t)b*SS + qrow0 + q)*FF1 + h*HDD + kk*32 + g*8);

  auto issueK = [&](int kt, int buf){
    size_t kvrow = (size_t)b*SS + kt*64;
    #pragma unroll
    for (int i = 0; i < 2; ++i){
      int c = i*256 + tid;
      int row = c >> 3, seg = (c & 7) ^ (row & 7);
      GLOAD_LDS16(qkv + (kvrow + row)*FF1 + DD + h*HDD + seg*8,
                  lsK[buf] + (size_t)(i*256 + wid*64)*8);
    }
  };
  auto issueV = [&](int kt, half8* vr){
    size_t kvrow = (size_t)b*SS + kt*64;
    #pragma unroll
    for (int i = 0; i < 2; ++i)
      vr[i] = *(const half8*)(qkv + (kvrow + lane)*FF1 + 2*DD + h*HDD + (wid*2+i)*8);
  };
  auto writeV = [&](const half8* vr, int buf){
    #pragma unroll
    for (int i = 0; i < 2; ++i){
      int p = wid*2 + i;
      #pragma unroll
      for (int j = 0; j < 8; ++j){
        int hd = p*8 + j;
        lsV[buf][hd*64 + (lane ^ ((hd & 7) << 3))] = vr[i][j];
      }
    }
  };

  f32x4 o[4] = {};
  float mrow = -1e30f, lsum = 0.f;     // stats for qrow = q (log2 domain)
  const float SC2 = 0.18033688011112042f;  // log2(e)/8
  int qglob = qrow0 + q;

  half8 vr[2];
  issueK(0, 0);          // 2 gloads outstanding
  issueV(0, vr);         // +2 = 4 outstanding

  for (int kt = 0; kt <= qt; ++kt){
    int cur = kt & 1, nxt = cur ^ 1;
    int tn = (kt < qt) ? kt+1 : qt;    // clamp: last iter re-issues (harmless)
    asm volatile("s_waitcnt vmcnt(2)" ::: "memory");   // K(kt) landed in lsK[cur]
    SBAR();                            // all waves: K ready; prev PV reads done

    f32x4 st[4] = {};                  // S^T frags: row=key(g*4+r,+16i), col=qrow(q)
    #pragma unroll
    for (int i = 0; i < 4; ++i){
      #pragma unroll
      for (int kk = 0; kk < 2; ++kk){
        half8 kf = *(const half8*)(lsK[cur] + (i*16 + q)*64 + ((kk*32 + g*8) ^ xo));
        st[i] = mfma16(kf, qf[kk], st[i]);
      }
    }
    issueK(tn, nxt);                   // prefetch K(t+1) (lsK[nxt] free since prev barrier)
    asm volatile("s_waitcnt vmcnt(2)" ::: "memory");   // V(kt) regs arrived
    writeV(vr, cur);                   // lsV[cur] free since prev barrier

    float pvv[16]; float tm = -1e30f;
    #pragma unroll
    for (int i = 0; i < 4; ++i)
      #pragma unroll
      for (int r = 0; r < 4; ++r){
        int kglob = kt*64 + i*16 + g*4 + r;
        float sv = (kglob <= qglob) ? st[i][r]*SC2 : -1e30f;
        pvv[i*4+r] = sv; tm = fmaxf(tm, sv);
      }
    tm = fmaxf(tm, __shfl_xor(tm, 16, 64));
    tm = fmaxf(tm, __shfl_xor(tm, 32, 64));
    float mnew  = fmaxf(mrow, tm);
    float alpha = exp2f(mrow - mnew);
    mrow = mnew;
    float psum = 0.f;
    _Float16 pb[16];
    #pragma unroll
    for (int i = 0; i < 16; ++i){
      float p = exp2f(pvv[i] - mnew);
      psum += p; pb[i] = (_Float16)p;
    }
    lsum = lsum*alpha + psum;
    float af4[4];
    #pragma unroll
    for (int r = 0; r < 4; ++r) af4[r] = __shfl(alpha, g*4 + r, 64);
    #pragma unroll
    for (int n = 0; n < 4; ++n)
      #pragma unroll
      for (int r = 0; r < 4; ++r) o[n][r] *= af4[r];
    issueV(tn, vr);                    // prefetch V(t+1) into regs

    asm volatile("s_waitcnt lgkmcnt(0)" ::: "memory"); // V ds_writes visible
    SBAR();                            // all waves wrote lsV[cur]

    #pragma unroll
    for (int i = 0; i < 4; ++i){       // P -> wave-private LDS (swizzled)
      half4 w4;
      w4[0]=pb[i*4+0]; w4[1]=pb[i*4+1]; w4[2]=pb[i*4+2]; w4[3]=pb[i*4+3];
      *(half4*)(&lsP[wid][q*64 + ((i*16 + g*4) ^ xo)]) = w4;
    }
    #pragma unroll
    for (int kk = 0; kk < 2; ++kk){    // O += P * V
      half8 pf = *(const half8*)(&lsP[wid][q*64 + ((kk*32 + g*8) ^ xo)]);
      #pragma unroll
      for (int n = 0; n < 4; ++n){
        half8 vf = *(const half8*)(&lsV[cur][(n*16 + q)*64 + ((kk*32 + g*8) ^ xo)]);
        o[n] = mfma16(pf, vf, o[n]);
      }
    }
  }
  float lt = lsum + __shfl_xor(lsum, 16, 64);
  lt = lt + __shfl_xor(lt, 32, 64);
  float rinv = 1.f / lt;
  #pragma unroll
  for (int r = 0; r < 4; ++r){
    float ri = __shfl(rinv, g*4 + r, 64);
    int qg = qt*64 + wid*16 + g*4 + r;
    _Float16* obase = ctx + ((size_t)b*SS + qg)*DD + h*HDD;
    #pragma unroll
    for (int n = 0; n < 4; ++n)
      obase[n*16 + q] = (_Float16)(o[n][r] * ri);
  }
}

// ---------------------------------------------------------------------------
extern "C" void kernel_launch(void* const* d_in, const int* in_sizes, int n_in,
                              void* d_out, int out_size, void* d_ws, size_t ws_size,
                              hipStream_t stream)
{
  const float* x      = (const float*)d_in[0];
  const float* Wr     = (const float*)d_in[1];
  const float* br     = (const float*)d_in[2];
  const float* ln_g   = (const float*)d_in[3];
  const float* ln_b   = (const float*)d_in[4];
  const float* W_attn = (const float*)d_in[5];
  const float* b_attn = (const float*)d_in[6];
  const float* W_proj = (const float*)d_in[7];
  const float* b_proj = (const float*)d_in[8];
  (void)in_sizes; (void)n_in; (void)out_size; (void)ws_size;

  char* ws = (char*)d_ws;
  size_t off = 0;
  auto alloc = [&](size_t bytes) -> void* {
    void* p = ws + off; off += (bytes + 255) & ~(size_t)255; return p;
  };
  _Float16* W1gT  = (_Float16*)alloc((size_t)FF1*KK2*2);   // 25.2 MB (g folded)
  _Float16* W2T   = (_Float16*)alloc((size_t)DD*KK2*2);    //  8.4 MB
  float*    score = (float*)   alloc((size_t)NN*4*4);      // 64 KB
  float*    ratio = (float*)   alloc((size_t)NN*4*4);      // 64 KB
  _Float16* xn16  = (_Float16*)alloc((size_t)NN*DD*2);     //  8.4 MB
  _Float16* qkv   = (_Float16*)alloc((size_t)NN*FF1*2);    // 25.2 MB
  _Float16* ctx   = (_Float16*)alloc((size_t)NN*DD*2);     //  8.4 MB
  float*    part  = (float*)   alloc((size_t)(KK2/64)*FF1*4); // 786 KB
  float*    BB1   = (float*)   alloc((size_t)EE*FF1*4);    // 48 KB

  hipLaunchKernelGGL((transpose_f16_kernel<true>), dim3(KK2/64, FF1/64), dim3(256), 0, stream,
                     W_attn, W1gT, KK2, FF1, ln_g, ln_b, part);
  hipLaunchKernelGGL((transpose_f16_kernel<false>), dim3(KK2/64, DD/64), dim3(256), 0, stream,
                     W_proj, W2T, KK2, DD, nullptr, nullptr, nullptr);
  hipLaunchKernelGGL(bb1_kernel, dim3(EE*FF1/256), dim3(256), 0, stream,
                     b_attn, part, BB1);
  hipLaunchKernelGGL(prep_kernel, dim3(NN), dim3(256), 0, stream,
                     x, Wr, br, score, ratio, xn16);
  hipLaunchKernelGGL(gemm1_kernel, dim3(256), dim3(512), 0, stream,
                     xn16, W1gT, score, ratio, BB1, qkv);
  hipLaunchKernelGGL(attn_kernel, dim3(NB*HH, SS/64), dim3(256), 0, stream,
                     qkv, ctx);
  hipLaunchKernelGGL(gemm2_kernel, dim3(256), dim3(512), 0, stream,
                     ctx, W2T, score, b_proj, (float*)d_out);
}

// Round 8
// 199.758 us; speedup vs baseline: 1.1651x; 1.0350x over previous
//
#include <hip/hip_runtime.h>
#include <stdint.h>

#define NB 4
#define SS 1024
#define DD 1024
#define EE 4
#define HH 16
#define HDD 64
#define NN (NB*SS)      // 4096 tokens
#define KK2 (EE*DD)     // 4096 expanded K
#define FF1 (3*DD)      // 3072

typedef __attribute__((ext_vector_type(4))) float f32x4;
typedef __attribute__((ext_vector_type(8))) _Float16 half8;
typedef __attribute__((ext_vector_type(4))) _Float16 half4;

static __device__ __forceinline__ f32x4 mfma16(half8 a, half8 b, f32x4 c){
  return __builtin_amdgcn_mfma_f32_16x16x32_f16(a, b, c, 0, 0, 0);
}

// async global->LDS, 16B per lane; LDS dest = wave-uniform base + lane*16
#define GLOAD_LDS16(gp, lp) __builtin_amdgcn_global_load_lds( \
    (const unsigned int __attribute__((address_space(1)))*)(uintptr_t)(gp), \
    (unsigned int __attribute__((address_space(3)))*)(uintptr_t)(lp), 16, 0, 0)

#define SBAR() do { asm volatile("" ::: "memory"); \
                    __builtin_amdgcn_s_barrier(); \
                    asm volatile("" ::: "memory"); } while(0)

// ---------------- kernel 1: router softmax + LN stats + xn (f16) -----------
__global__ __launch_bounds__(256) void prep_kernel(
    const float* __restrict__ x, const float* __restrict__ Wr,
    const float* __restrict__ br, float* __restrict__ score,
    float* __restrict__ ratios, _Float16* __restrict__ xnb)
{
  int n = blockIdx.x;
  int tid = threadIdx.x;
  float4 xv = ((const float4*)(x + (size_t)n*DD))[tid];   // d = tid*4..+3
  float xa[4] = {xv.x, xv.y, xv.z, xv.w};
  float vals[6];
  vals[0] = xa[0]+xa[1]+xa[2]+xa[3];
  vals[1] = xa[0]*xa[0]+xa[1]*xa[1]+xa[2]*xa[2]+xa[3]*xa[3];
  vals[2] = vals[3] = vals[4] = vals[5] = 0.f;
  #pragma unroll
  for (int j = 0; j < 4; ++j){
    float4 w = ((const float4*)Wr)[tid*4 + j];  // Wr row d = 4 expert weights
    vals[2] += xa[j]*w.x; vals[3] += xa[j]*w.y;
    vals[4] += xa[j]*w.z; vals[5] += xa[j]*w.w;
  }
  #pragma unroll
  for (int off = 32; off >= 1; off >>= 1)
    #pragma unroll
    for (int i = 0; i < 6; ++i)
      vals[i] += __shfl_xor(vals[i], off, 64);
  __shared__ float red[4][6];
  int wid = tid >> 6;
  if ((tid & 63) == 0){
    #pragma unroll
    for (int i = 0; i < 6; ++i) red[wid][i] = vals[i];
  }
  __syncthreads();
  float tot[6];
  #pragma unroll
  for (int i = 0; i < 6; ++i)
    tot[i] = red[0][i] + red[1][i] + red[2][i] + red[3][i];

  float mu   = tot[0] * (1.f/DD);
  float var  = tot[1] * (1.f/DD) - mu*mu;
  float rsig = rsqrtf(var + 1e-5f);
  float lg[4];
  #pragma unroll
  for (int e = 0; e < 4; ++e) lg[e] = tot[2+e] + br[e];
  float mx = fmaxf(fmaxf(lg[0], lg[1]), fmaxf(lg[2], lg[3]));
  float ex[4], esum = 0.f;
  #pragma unroll
  for (int e = 0; e < 4; ++e){ ex[e] = __expf(lg[e] - mx); esum += ex[e]; }
  if (tid < 4){
    score[n*4 + tid] = ex[tid] / esum;
    ratios[n*4 + tid] = (tid > 0) ? (ex[tid-1] / ex[tid]) : 0.f;
  }

  half4 o;
  #pragma unroll
  for (int j = 0; j < 4; ++j) o[j] = (_Float16)((xa[j] - mu) * rsig);
  *(half4*)(xnb + (size_t)n*DD + tid*4) = o;
}

// ---------------- kernel 2: W [K,F] fp32 -> WT [F,K] f16 --------------------
// AFFINE: WT = g[k]*W (LN gain folded along K); part[kt,f] = sum_k b[k]*W[k,f]
template<bool AFFINE>
__global__ __launch_bounds__(256) void transpose_f16_kernel(
    const float* __restrict__ W, _Float16* __restrict__ WT, int K, int F,
    const float* __restrict__ gvec, const float* __restrict__ bvec,
    float* __restrict__ part)
{
  __shared__ float t[64][65];
  __shared__ float red2[16][64];
  int k0 = blockIdx.x * 64, f0 = blockIdx.y * 64;
  int tid = threadIdx.x;
  int r = tid >> 4, c4 = (tid & 15) * 4;
  float pf[4] = {0.f, 0.f, 0.f, 0.f};
  #pragma unroll
  for (int i = 0; i < 4; ++i){
    int k = k0 + i*16 + r;
    float4 v = *(const float4*)(W + (size_t)k*F + f0 + c4);
    if constexpr (AFFINE){
      float bk = bvec[k];
      pf[0] += bk*v.x; pf[1] += bk*v.y; pf[2] += bk*v.z; pf[3] += bk*v.w;
      float gk = gvec[k];
      v.x *= gk; v.y *= gk; v.z *= gk; v.w *= gk;
    }
    t[i*16 + r][c4+0] = v.x; t[i*16 + r][c4+1] = v.y;
    t[i*16 + r][c4+2] = v.z; t[i*16 + r][c4+3] = v.w;
  }
  if constexpr (AFFINE){
    #pragma unroll
    for (int j = 0; j < 4; ++j) red2[r][c4+j] = pf[j];
  }
  __syncthreads();
  int f = tid >> 2, seg = tid & 3;
  half8 o0, o1;
  #pragma unroll
  for (int j = 0; j < 8; ++j){
    o0[j] = (_Float16)t[seg*16 + j][f];
    o1[j] = (_Float16)t[seg*16 + 8 + j][f];
  }
  _Float16* dst = WT + (size_t)(f0 + f)*K + k0 + seg*16;
  *(half8*)dst = o0;
  *(half8*)(dst + 8) = o1;
  if constexpr (AFFINE){
    if (tid < 64){
      float s = 0.f;
      #pragma unroll
      for (int rr = 0; rr < 16; ++rr) s += red2[rr][tid];
      part[(size_t)blockIdx.x * F + f0 + tid] = s;
    }
  }
}

// ---------------- BB1[e,f] = b_attn[e,f] + sum_i part[e*16+i, f] ------------
__global__ __launch_bounds__(256) void bb1_kernel(
    const float* __restrict__ b_attn, const float* __restrict__ part,
    float* __restrict__ BB1)
{
  int idx = blockIdx.x*256 + threadIdx.x;   // e*FF1 + f
  int e = idx / FF1, f = idx - e*FF1;
  float s = b_attn[idx];
  #pragma unroll
  for (int i = 0; i < 16; ++i)
    s += part[(size_t)(e*16 + i)*FF1 + f];
  BB1[idx] = s;
}

// ---------------- GEMM1: qkv[4096,3072] = sum_e s_e*(xn @ W1g_e) + bias -----
// 256x192 tile, BK=64, 8 waves (4M x 2N), dbuf, counted vmcnt, 4-phase (T3),
// setprio (T5), XOR-swizzle (T2), reads-before-barrier hoist (m201 discipline)
// for ph1/ph2. score via TELESCOPING acc rescale; s3 folded in epilogue.
#define G1_BM 256
#define G1_BN 192
#define G1_BK 64
#define G1_T  (KK2/G1_BK)            // 64 K-tiles (16 per expert)
#define G1_ABUF (G1_BM*G1_BK)        // 16384 f16
#define G1_BBUF (G1_BN*G1_BK)        // 12288 f16
#define G1_BUFSZ (G1_ABUF+G1_BBUF)   // 28672 f16 per buffer

__global__ __launch_bounds__(512, 2) void gemm1_kernel(
    const _Float16* __restrict__ XN, const _Float16* __restrict__ BT,
    const float* __restrict__ score, const float* __restrict__ ratios,
    const float* __restrict__ bias, _Float16* __restrict__ C)
{
  __shared__ _Float16 smem[2*G1_BUFSZ];   // 112 KiB
  int tid = threadIdx.x;
  int lane = tid & 63, wid = tid >> 6;
  int q = lane & 15, g = lane >> 4;
  int wr = wid >> 1, wc = wid & 1;
  int xo = (q & 7) << 3;
  int bid = blockIdx.x;
  int xcd = bid & 7, li = bid >> 3;
  int m0 = (li >> 1) * G1_BM;
  int n0 = (xcd*2 + (li & 1)) * G1_BN;

  int arow[4], brow[6];
  #pragma unroll
  for (int mf = 0; mf < 4; ++mf) arow[mf] = (wr*64 + mf*16 + q)*64;
  #pragma unroll
  for (int nf = 0; nf < 6; ++nf) brow[nf] = G1_ABUF + (wc*96 + nf*16 + q)*64;
  int soff[2] = { (g*8) ^ xo, (32 + g*8) ^ xo };

  auto stageA = [&](int t, int buf, int h){
    const int d0 = (t & 15) * G1_BK;
    _Float16* sA = smem + buf*G1_BUFSZ;
    #pragma unroll
    for (int ld = 0; ld < 2; ++ld){
      int l = h*2 + ld;
      int c = l*512 + tid;
      int row = c >> 3;
      int seg = (c & 7) ^ (row & 7);     // inverse-swizzled global source
      GLOAD_LDS16(XN + (size_t)(m0 + row)*DD + d0 + seg*8,
                  sA + (l*512 + wid*64)*8);
    }
  };
  auto stageB = [&](int t, int buf){
    const int k0 = t * G1_BK;
    _Float16* sB = smem + buf*G1_BUFSZ + G1_ABUF;
    #pragma unroll
    for (int ld = 0; ld < 3; ++ld){
      int c = ld*512 + tid;
      int row = c >> 3;
      int seg = (c & 7) ^ (row & 7);
      GLOAD_LDS16(BT + (size_t)(n0 + row)*KK2 + k0 + seg*8,
                  sB + (ld*512 + wid*64)*8);
    }
  };

  f32x4 acc[4][6] = {};
  half8 af0[2][2], af2[2][2], bf[6][2];

  stageA(0, 0, 0); stageA(0, 0, 1); stageB(0, 0);

  for (int t = 0; t < G1_T-1; ++t){
    if (t && (t & 15) == 0){              // expert boundary: acc *= s_{e-1}/s_e
      int e = t >> 4;
      #pragma unroll
      for (int mf = 0; mf < 4; ++mf)
        #pragma unroll
        for (int r = 0; r < 4; ++r){
          int gm = m0 + wr*64 + mf*16 + g*4 + r;
          float ratio = ratios[gm*4 + e];
          #pragma unroll
          for (int nf = 0; nf < 6; ++nf)
            acc[mf][nf][r] *= ratio;
        }
    }
    int buf = t & 1, nxt = buf ^ 1;
    const _Float16* base = smem + buf*G1_BUFSZ;
    stageA(t+1, nxt, 0);                           // 2 loads -> 9 outstanding
    asm volatile("s_waitcnt vmcnt(2)" ::: "memory");  // tile t (oldest 7) landed
    SBAR();                                        // rendezvous: buf(t) ready
    // ---- ph0 reads (cannot hoist across the staging rendezvous) ----
    #pragma unroll
    for (int m = 0; m < 2; ++m)
      #pragma unroll
      for (int k = 0; k < 2; ++k)
        af0[m][k] = *(const half8*)(base + arow[m] + soff[k]);
    #pragma unroll
    for (int n = 0; n < 3; ++n)
      #pragma unroll
      for (int k = 0; k < 2; ++k)
        bf[n][k] = *(const half8*)(base + brow[n] + soff[k]);
    stageA(t+1, nxt, 1);
    __builtin_amdgcn_s_setprio(1);
    #pragma unroll
    for (int k = 0; k < 2; ++k)
      #pragma unroll
      for (int m = 0; m < 2; ++m)
        #pragma unroll
        for (int n = 0; n < 3; ++n)
          acc[m][n] = mfma16(af0[m][k], bf[n][k], acc[m][n]);
    __builtin_amdgcn_s_setprio(0);
    // ---- ph1 reads HOISTED pre-barrier (latency hides under barrier) ----
    #pragma unroll
    for (int n = 3; n < 6; ++n)
      #pragma unroll
      for (int k = 0; k < 2; ++k)
        bf[n][k] = *(const half8*)(base + brow[n] + soff[k]);
    stageB(t+1, nxt);
    SBAR();
    __builtin_amdgcn_s_setprio(1);
    #pragma unroll
    for (int k = 0; k < 2; ++k)
      #pragma unroll
      for (int m = 0; m < 2; ++m)
        #pragma unroll
        for (int n = 3; n < 6; ++n)
          acc[m][n] = mfma16(af0[m][k], bf[n][k], acc[m][n]);
    __builtin_amdgcn_s_setprio(0);
    // ---- ph2 reads HOISTED pre-barrier ----
    #pragma unroll
    for (int m = 0; m < 2; ++m)
      #pragma unroll
      for (int k = 0; k < 2; ++k)
        af2[m][k] = *(const half8*)(base + arow[2+m] + soff[k]);
    SBAR();
    __builtin_amdgcn_s_setprio(1);
    #pragma unroll
    for (int k = 0; k < 2; ++k)
      #pragma unroll
      for (int m = 0; m < 2; ++m)
        #pragma unroll
        for (int n = 3; n < 6; ++n)
          acc[2+m][n] = mfma16(af2[m][k], bf[n][k], acc[2+m][n]);
    // ---- ph3: m23 x n012 (regs only; overlaps next tile's top) ----
    #pragma unroll
    for (int k = 0; k < 2; ++k)
      #pragma unroll
      for (int m = 0; m < 2; ++m)
        #pragma unroll
        for (int n = 0; n < 3; ++n)
          acc[2+m][n] = mfma16(af2[m][k], bf[n][k], acc[2+m][n]);
    __builtin_amdgcn_s_setprio(0);
  }
  // ---- last tile (expert 3, no boundary) ----
  {
    const _Float16* base = smem + ((G1_T-1) & 1)*G1_BUFSZ;
    asm volatile("s_waitcnt vmcnt(0)" ::: "memory");
    SBAR();
    #pragma unroll
    for (int m = 0; m < 2; ++m)
      #pragma unroll
      for (int k = 0; k < 2; ++k){
        af0[m][k] = *(const half8*)(base + arow[m] + soff[k]);
        af2[m][k] = *(const half8*)(base + arow[2+m] + soff[k]);
      }
    #pragma unroll
    for (int n = 0; n < 6; ++n)
      #pragma unroll
      for (int k = 0; k < 2; ++k)
        bf[n][k] = *(const half8*)(base + brow[n] + soff[k]);
    #pragma unroll
    for (int k = 0; k < 2; ++k)
      #pragma unroll
      for (int m = 0; m < 2; ++m)
        #pragma unroll
        for (int n = 0; n < 6; ++n){
          acc[m][n]   = mfma16(af0[m][k], bf[n][k], acc[m][n]);
          acc[2+m][n] = mfma16(af2[m][k], bf[n][k], acc[2+m][n]);
        }
  }

  // epilogue: v = acc*s3 + sum_e score[m,e]*BB1[e,n], f16 store
  float bv[6][4];
  #pragma unroll
  for (int nf = 0; nf < 6; ++nf){
    int gn = n0 + wc*96 + nf*16 + q;
    #pragma unroll
    for (int e = 0; e < 4; ++e) bv[nf][e] = bias[e*FF1 + gn];
  }
  #pragma unroll
  for (int mf = 0; mf < 4; ++mf){
    #pragma unroll
    for (int r = 0; r < 4; ++r){
      int gm = m0 + wr*64 + mf*16 + g*4 + r;
      float4 sc = *(const float4*)(score + gm*4);
      #pragma unroll
      for (int nf = 0; nf < 6; ++nf){
        int gn = n0 + wc*96 + nf*16 + q;
        float v = acc[mf][nf][r]*sc.w
                + sc.x*bv[nf][0] + sc.y*bv[nf][1] + sc.z*bv[nf][2] + sc.w*bv[nf][3];
        C[(size_t)gm*FF1 + gn] = (_Float16)v;
      }
    }
  }
}

// ---------------- GEMM2: out = sum_e s_e*(ctx @ W2_e) + bias ----------------
// 128x128 tile, BK=64, 8 waves (2M x 4N), dbuf, counted vmcnt(4), 2-phase
// compute with kk1-reads hoisted pre-barrier. Per-expert acc split.
#define G2_BK 64
#define G2_ABUF (128*G2_BK)
#define G2_BUFSZ (2*G2_ABUF)         // A+B per buffer = 32 KiB

__global__ __launch_bounds__(512) void gemm2_kernel(
    const _Float16* __restrict__ CTX, const _Float16* __restrict__ BT,
    const float* __restrict__ score, const float* __restrict__ bias,
    float* __restrict__ Cout)
{
  __shared__ _Float16 smem[2*G2_BUFSZ];   // 64 KiB
  int tid = threadIdx.x;
  int lane = tid & 63, wid = tid >> 6;
  int q = lane & 15, g = lane >> 4;
  int wr = wid >> 2, wc = wid & 3;     // 2M x 4N
  int xo = (q & 7) << 3;
  int bid = blockIdx.x;
  int xcd = bid >> 5, idx = bid & 31;
  int m0 = (xcd*4 + (idx >> 3)) * 128;
  int n0 = (idx & 7) * 128;

  int arow[4], brow[2];
  #pragma unroll
  for (int mf = 0; mf < 4; ++mf) arow[mf] = (wr*64 + mf*16 + q)*64;
  #pragma unroll
  for (int nf = 0; nf < 2; ++nf) brow[nf] = G2_ABUF + (wc*32 + nf*16 + q)*64;
  int soff[2] = { (g*8) ^ xo, (32 + g*8) ^ xo };

  auto stage = [&](int t, int buf){
    const int d0 = (t & 15) * G2_BK;
    const int k0 = t * G2_BK;
    _Float16* sA = smem + buf*G2_BUFSZ;
    _Float16* sB = sA + G2_ABUF;
    #pragma unroll
    for (int ld = 0; ld < 2; ++ld){
      int c = ld*512 + tid;
      int row = c >> 3;
      int seg = (c & 7) ^ (row & 7);
      GLOAD_LDS16(CTX + (size_t)(m0 + row)*DD + d0 + seg*8,
                  sA + (ld*512 + wid*64)*8);
    }
    #pragma unroll
    for (int ld = 0; ld < 2; ++ld){
      int c = ld*512 + tid;
      int row = c >> 3;
      int seg = (c & 7) ^ (row & 7);
      GLOAD_LDS16(BT + (size_t)(n0 + row)*KK2 + k0 + seg*8,
                  sB + (ld*512 + wid*64)*8);
    }
  };

  f32x4 accp[4][2] = {}, acco[4][2] = {};

  auto merge = [&](int e){
    #pragma unroll
    for (int m = 0; m < 4; ++m)
      #pragma unroll
      for (int r = 0; r < 4; ++r){
        int gm = m0 + wr*64 + m*16 + g*4 + r;
        float s = score[(size_t)gm*4 + e];
        #pragma unroll
        for (int n = 0; n < 2; ++n){
          acco[m][n][r] += s*accp[m][n][r];
          accp[m][n][r] = 0.f;
        }
      }
  };

  half8 af[4][2], bfr[2][2];
  auto reads = [&](const _Float16* base, int k){
    #pragma unroll
    for (int m = 0; m < 4; ++m)
      af[m][k] = *(const half8*)(base + arow[m] + soff[k]);
    #pragma unroll
    for (int n = 0; n < 2; ++n)
      bfr[n][k] = *(const half8*)(base + brow[n] + soff[k]);
  };
  auto mfmas = [&](int k){
    __builtin_amdgcn_s_setprio(1);
    #pragma unroll
    for (int m = 0; m < 4; ++m)
      #pragma unroll
      for (int n = 0; n < 2; ++n)
        accp[m][n] = mfma16(af[m][k], bfr[n][k], accp[m][n]);
    __builtin_amdgcn_s_setprio(0);
  };

  stage(0, 0);
  for (int t = 0; t < KK2/G2_BK - 1; ++t){
    const _Float16* base = smem + (t & 1)*G2_BUFSZ;
    stage(t+1, (t+1)&1);
    asm volatile("s_waitcnt vmcnt(4)" ::: "memory");  // tile t landed
    SBAR();
    reads(base, 0);
    mfmas(0);
    reads(base, 1);            // hoisted pre-barrier
    SBAR();                    // reads of buf(t) all issued -> restage safe next iter
    mfmas(1);
    if ((t & 15) == 15) merge(t >> 4);                // expert boundary
  }
  {
    const _Float16* base = smem + ((KK2/G2_BK - 1) & 1)*G2_BUFSZ;
    asm volatile("s_waitcnt vmcnt(0)" ::: "memory");
    SBAR();
    reads(base, 0); reads(base, 1);
    mfmas(0); mfmas(1);
    merge(3);
  }

  #pragma unroll
  for (int m = 0; m < 4; ++m){
    #pragma unroll
    for (int r = 0; r < 4; ++r){
      int gm = m0 + wr*64 + m*16 + g*4 + r;
      float4 sc = *(const float4*)(score + gm*4);
      #pragma unroll
      for (int n = 0; n < 2; ++n){
        int gn = n0 + wc*32 + n*16 + q;
        float v = acco[m][n][r]
                + sc.x*bias[gn] + sc.y*bias[DD+gn]
                + sc.z*bias[2*DD+gn] + sc.w*bias[3*DD+gn];
        Cout[(size_t)gm*DD + gn] = v;
      }
    }
  }
}

// ---------------- kernel 4: causal flash attention, QBLK=128, 8 waves -------
// Per block: 128 q-rows (wave w owns 16), KV tiles of 64 staged ONCE for all
// 8 waves (halves staging vs QBLK=64). Pipelined K (gload_lds dbuf) + V
// (reg-staged dbuf), counted vmcnt(1); raw barriers + lgkmcnt only.
__global__ __launch_bounds__(512) void attn_kernel(
    const _Float16* __restrict__ qkv, _Float16* __restrict__ ctx)
{
  __shared__ _Float16 lsK[2][64*64];   // [key][hd], swizzled
  __shared__ _Float16 lsV[2][64*64];   // [hd][key], swizzled (transposed)
  __shared__ _Float16 lsP[8][16*64];   // per-wave P [qrow][key], swizzled
  int bh = blockIdx.x, qt = blockIdx.y;         // qt in 0..7 (128-row tiles)
  int b = bh >> 4, h = bh & 15;
  int tid = threadIdx.x, lane = tid & 63, wid = tid >> 6;   // wid 0..7
  int q = lane & 15, g = lane >> 4;
  int xo = (q & 7) << 3;
  int qrow0 = qt*128 + wid*16;

  half8 qf[2];
  #pragma unroll
  for (int kk = 0; kk < 2; ++kk)
    qf[kk] = *(const half8*)(qkv + ((size_t)b*SS + qrow0 + q)*FF1 + h*HDD + kk*32 + g*8);

  auto issueK = [&](int kt, int buf){   // one gload_lds per wave (512 lanes = 8KB tile)
    size_t kvrow = (size_t)b*SS + kt*64;
    int row = tid >> 3, seg = (tid & 7) ^ (row & 7);
    GLOAD_LDS16(qkv + (kvrow + row)*FF1 + DD + h*HDD + seg*8,
                lsK[buf] + (size_t)(wid*64)*8);
  };
  auto issueV = [&](int kt, half8& vr){ // wave w covers hd cols w*8..w*8+7
    size_t kvrow = (size_t)b*SS + kt*64;
    vr = *(const half8*)(qkv + (kvrow + lane)*FF1 + 2*DD + h*HDD + wid*8);
  };
  auto writeV = [&](half8 vr, int buf){
    #pragma unroll
    for (int j = 0; j < 8; ++j){
      int hd = wid*8 + j;
      lsV[buf][hd*64 + (lane ^ ((hd & 7) << 3))] = vr[j];
    }
  };

  f32x4 o[4] = {};
  float mrow = -1e30f, lsum = 0.f;     // stats for qrow = q (log2 domain)
  const float SC2 = 0.18033688011112042f;  // log2(e)/8
  int qglob = qrow0 + q;
  int ktmax = 2*qt + 1;

  half8 vr;
  issueK(0, 0);          // 1 gload outstanding
  issueV(0, vr);         // +1 = 2 outstanding

  for (int kt = 0; kt <= ktmax; ++kt){
    int cur = kt & 1, nxt = cur ^ 1;
    int tn = (kt < ktmax) ? kt+1 : ktmax;  // clamp: last iter re-issues (harmless)
    asm volatile("s_waitcnt vmcnt(1)" ::: "memory");   // K(kt) landed in lsK[cur]
    SBAR();                            // all waves: K ready; prev PV reads done

    f32x4 st[4] = {};                  // S^T frags: row=key(g*4+r,+16i), col=qrow(q)
    #pragma unroll
    for (int i = 0; i < 4; ++i){
      #pragma unroll
      for (int kk = 0; kk < 2; ++kk){
        half8 kf = *(const half8*)(lsK[cur] + (i*16 + q)*64 + ((kk*32 + g*8) ^ xo));
        st[i] = mfma16(kf, qf[kk], st[i]);
      }
    }
    issueK(tn, nxt);                   // prefetch K(t+1)
    asm volatile("s_waitcnt vmcnt(1)" ::: "memory");   // V(kt) regs arrived
    writeV(vr, cur);                   // lsV[cur] free since prev barrier

    float pvv[16]; float tm = -1e30f;
    #pragma unroll
    for (int i = 0; i < 4; ++i)
      #pragma unroll
      for (int r = 0; r < 4; ++r){
        int kglob = kt*64 + i*16 + g*4 + r;
        float sv = (kglob <= qglob) ? st[i][r]*SC2 : -1e30f;
        pvv[i*4+r] = sv; tm = fmaxf(tm, sv);
      }
    tm = fmaxf(tm, __shfl_xor(tm, 16, 64));
    tm = fmaxf(tm, __shfl_xor(tm, 32, 64));
    float mnew  = fmaxf(mrow, tm);
    float alpha = exp2f(mrow - mnew);
    mrow = mnew;
    float psum = 0.f;
    _Float16 pb[16];
    #pragma unroll
    for (int i = 0; i < 16; ++i){
      float p = exp2f(pvv[i] - mnew);
      psum += p; pb[i] = (_Float16)p;
    }
    lsum = lsum*alpha + psum;
    float af4[4];
    #pragma unroll
    for (int r = 0; r < 4; ++r) af4[r] = __shfl(alpha, g*4 + r, 64);
    #pragma unroll
    for (int n = 0; n < 4; ++n)
      #pragma unroll
      for (int r = 0; r < 4; ++r) o[n][r] *= af4[r];
    issueV(tn, vr);                    // prefetch V(t+1) into regs

    asm volatile("s_waitcnt lgkmcnt(0)" ::: "memory"); // V ds_writes visible
    SBAR();                            // all waves wrote lsV[cur]

    #pragma unroll
    for (int i = 0; i < 4; ++i){       // P -> wave-private LDS (swizzled)
      half4 w4;
      w4[0]=pb[i*4+0]; w4[1]=pb[i*4+1]; w4[2]=pb[i*4+2]; w4[3]=pb[i*4+3];
      *(half4*)(&lsP[wid][q*64 + ((i*16 + g*4) ^ xo)]) = w4;
    }
    #pragma unroll
    for (int kk = 0; kk < 2; ++kk){    // O += P * V
      half8 pf = *(const half8*)(&lsP[wid][q*64 + ((kk*32 + g*8) ^ xo)]);
      #pragma unroll
      for (int n = 0; n < 4; ++n){
        half8 vf = *(const half8*)(&lsV[cur][(n*16 + q)*64 + ((kk*32 + g*8) ^ xo)]);
        o[n] = mfma16(pf, vf, o[n]);
      }
    }
  }
  float lt = lsum + __shfl_xor(lsum, 16, 64);
  lt = lt + __shfl_xor(lt, 32, 64);
  float rinv = 1.f / lt;
  #pragma unroll
  for (int r = 0; r < 4; ++r){
    float ri = __shfl(rinv, g*4 + r, 64);
    int qg = qt*128 + wid*16 + g*4 + r;
    _Float16* obase = ctx + ((size_t)b*SS + qg)*DD + h*HDD;
    #pragma unroll
    for (int n = 0; n < 4; ++n)
      obase[n*16 + q] = (_Float16)(o[n][r] * ri);
  }
}

// ---------------------------------------------------------------------------
extern "C" void kernel_launch(void* const* d_in, const int* in_sizes, int n_in,
                              void* d_out, int out_size, void* d_ws, size_t ws_size,
                              hipStream_t stream)
{
  const float* x      = (const float*)d_in[0];
  const float* Wr     = (const float*)d_in[1];
  const float* br     = (const float*)d_in[2];
  const float* ln_g   = (const float*)d_in[3];
  const float* ln_b   = (const float*)d_in[4];
  const float* W_attn = (const float*)d_in[5];
  const float* b_attn = (const float*)d_in[6];
  const float* W_proj = (const float*)d_in[7];
  const float* b_proj = (const float*)d_in[8];
  (void)in_sizes; (void)n_in; (void)out_size; (void)ws_size;

  char* ws = (char*)d_ws;
  size_t off = 0;
  auto alloc = [&](size_t bytes) -> void* {
    void* p = ws + off; off += (bytes + 255) & ~(size_t)255; return p;
  };
  _Float16* W1gT  = (_Float16*)alloc((size_t)FF1*KK2*2);   // 25.2 MB (g folded)
  _Float16* W2T   = (_Float16*)alloc((size_t)DD*KK2*2);    //  8.4 MB
  float*    score = (float*)   alloc((size_t)NN*4*4);      // 64 KB
  float*    ratio = (float*)   alloc((size_t)NN*4*4);      // 64 KB
  _Float16* xn16  = (_Float16*)alloc((size_t)NN*DD*2);     //  8.4 MB
  _Float16* qkv   = (_Float16*)alloc((size_t)NN*FF1*2);    // 25.2 MB
  _Float16* ctx   = (_Float16*)alloc((size_t)NN*DD*2);     //  8.4 MB
  float*    part  = (float*)   alloc((size_t)(KK2/64)*FF1*4); // 786 KB
  float*    BB1   = (float*)   alloc((size_t)EE*FF1*4);    // 48 KB

  hipLaunchKernelGGL((transpose_f16_kernel<true>), dim3(KK2/64, FF1/64), dim3(256), 0, stream,
                     W_attn, W1gT, KK2, FF1, ln_g, ln_b, part);
  hipLaunchKernelGGL((transpose_f16_kernel<false>), dim3(KK2/64, DD/64), dim3(256), 0, stream,
                     W_proj, W2T, KK2, DD, nullptr, nullptr, nullptr);
  hipLaunchKernelGGL(bb1_kernel, dim3(EE*FF1/256), dim3(256), 0, stream,
                     b_attn, part, BB1);
  hipLaunchKernelGGL(prep_kernel, dim3(NN), dim3(256), 0, stream,
                     x, Wr, br, score, ratio, xn16);
  hipLaunchKernelGGL(gemm1_kernel, dim3(256), dim3(512), 0, stream,
                     xn16, W1gT, score, ratio, BB1, qkv);
  hipLaunchKernelGGL(attn_kernel, dim3(NB*HH, SS/128), dim3(512), 0, stream,
                     qkv, ctx);
  hipLaunchKernelGGL(gemm2_kernel, dim3(256), dim3(512), 0, stream,
                     ctx, W2T, score, b_proj, (float*)d_out);
}